// Round 7
// baseline (357.428 us; speedup 1.0000x reference)
//
#include <hip/hip_runtime.h>

#define B_  2
#define S_  2048
#define E_  2048
#define H_  16
#define D_  128
#define BS_ (B_*S_)

typedef __bf16 bf16_t;
typedef __bf16 bf16x8 __attribute__((ext_vector_type(8)));
typedef __bf16 bf16x4 __attribute__((ext_vector_type(4)));
typedef float  f32x4  __attribute__((ext_vector_type(4)));
typedef float  f32x16 __attribute__((ext_vector_type(16)));

// combined softmax scale: 1/sqrt(128) * log2(e), folded into Q projection
#define QSCALE 0.1275174131003543f

// ---------------- async global->LDS, 16B per lane per call ----------------
__device__ __forceinline__ void gld16(const bf16_t* g, bf16_t* l) {
    __builtin_amdgcn_global_load_lds(
        (const __attribute__((address_space(1))) void*)g,
        (__attribute__((address_space(3))) void*)l,
        16, 0, 0);
}

// ---------------- fused fp32 -> bf16 convert (x, kv, 4 weights) ----------------
__global__ void cvt_all(const float* __restrict__ s0, const float* __restrict__ s1,
                        const float* __restrict__ s2, const float* __restrict__ s3,
                        const float* __restrict__ s4, const float* __restrict__ s5,
                        bf16_t* d0, bf16_t* d1, bf16_t* d2,
                        bf16_t* d3, bf16_t* d4, bf16_t* d5)
{
    long i = ((long)blockIdx.x * blockDim.x + threadIdx.x) * 4;
    const float* s; bf16_t* d;
    if      (i <  8388608) { s = s0; d = d0; }
    else if (i < 16777216) { s = s1; d = d1; i -=  8388608; }
    else if (i < 20971520) { s = s2; d = d2; i -= 16777216; }
    else if (i < 21233664) { s = s3; d = d3; i -= 20971520; }
    else if (i < 21495808) { s = s4; d = d4; i -= 21233664; }
    else                   { s = s5; d = d5; i -= 21495808; }
    float4 v = *(const float4*)(s + i);
    bf16x4 o;
    o[0] = (bf16_t)v.x; o[1] = (bf16_t)v.y; o[2] = (bf16_t)v.z; o[3] = (bf16_t)v.w;
    *(bf16x4*)(d + i) = o;
}

// ========== GEMM tile core: 128x128 tile (m97 structure), gld16 K-loop ==========
// 4 waves as 2x2; per-wave 64x64 output = 4x4 fp32x4 frags; BK=64; LDS 32 KB.
// MFMA:ds_read = 32:16 per K-step (vs 16:12 at the old 128x64 tile).
// bias is pre-offset by caller; lcol in [0,128) indexes it.
template<int EP>
__device__ __forceinline__ void gemm_tile128(
    const bf16_t* __restrict__ A, const bf16_t* __restrict__ W,
    const float* __restrict__ bias,
    float* __restrict__ Cf, bf16_t* __restrict__ Cb,
    int N, int K, float scale, int m0, int w_n0, int c_n0,
    bf16_t* As, bf16_t* Bs)
{
    const int tid  = threadIdx.x;
    const int wave = tid >> 6, lane = tid & 63;
    const int wm = wave >> 1, wn = wave & 1;
    const int lrow = lane & 15, quad = lane >> 4;
    const int r8 = lane >> 3, c8 = (lane & 7) << 3;

    f32x4 acc[4][4] = {};

    for (int k0 = 0; k0 < K; k0 += 64) {
        __syncthreads();
        // A: 128x64 bf16 = 16 KB, 4 gld16/thread (8 rows per call)
#pragma unroll
        for (int j = 0; j < 4; ++j) {
            int base = (wave * 4 + j) * 8;
            gld16(A + (size_t)(m0 + base + r8) * K + k0 + c8, &As[base * 64]);
        }
        // B: 128x64 bf16 = 16 KB, 4 gld16/thread
#pragma unroll
        for (int j = 0; j < 4; ++j) {
            int base = (wave * 4 + j) * 8;
            gld16(W + (size_t)(w_n0 + base + r8) * K + k0 + c8, &Bs[base * 64]);
        }
        __syncthreads();
#pragma unroll
        for (int ks = 0; ks < 2; ++ks) {
            bf16x8 af[4], bfr[4];
#pragma unroll
            for (int mt = 0; mt < 4; ++mt)
                af[mt] = *(const bf16x8*)&As[(wm * 64 + mt * 16 + lrow) * 64 + ks * 32 + quad * 8];
#pragma unroll
            for (int nt = 0; nt < 4; ++nt)
                bfr[nt] = *(const bf16x8*)&Bs[(wn * 64 + nt * 16 + lrow) * 64 + ks * 32 + quad * 8];
#pragma unroll
            for (int mt = 0; mt < 4; ++mt)
#pragma unroll
                for (int nt = 0; nt < 4; ++nt)
                    acc[mt][nt] = __builtin_amdgcn_mfma_f32_16x16x32_bf16(
                        af[mt], bfr[nt], acc[mt][nt], 0, 0, 0);
        }
    }

#pragma unroll
    for (int mt = 0; mt < 4; ++mt) {
#pragma unroll
        for (int nt = 0; nt < 4; ++nt) {
            int lcol = wn * 64 + nt * 16 + lrow;
            int col = c_n0 + lcol;
            float bvv = bias[lcol];
#pragma unroll
            for (int r = 0; r < 4; ++r) {
                int row = m0 + wm * 64 + mt * 16 + quad * 4 + r;
                float v = (acc[mt][nt][r] + bvv) * scale;
                if (EP == 0) Cf[(size_t)row * N + col] = v;
                else         Cb[(size_t)row * N + col] = (bf16_t)v;
            }
        }
    }
}

// ---------------- fused Q + K + V projection ----------------
// grid (18, 32): x<16 -> Q col-tile x (128 cols, scale QSCALE);
// x==16 -> K cols (Wkv rows 0..127); x==17 -> V cols (Wkv rows 128..255).
__global__ __launch_bounds__(256) void gemm_qkv(
    const bf16_t* __restrict__ xb, const bf16_t* __restrict__ kvb,
    const bf16_t* __restrict__ Wq, const bf16_t* __restrict__ Wkv,
    const float* __restrict__ bq, const float* __restrict__ bk,
    const float* __restrict__ bv,
    bf16_t* __restrict__ Qb, bf16_t* __restrict__ KVb)
{
    __shared__ __align__(16) bf16_t As[128 * 64];
    __shared__ __align__(16) bf16_t Bs[128 * 64];
    const int m0 = blockIdx.y * 128;
    const int x = blockIdx.x;
    if (x < 16) {
        int n0 = x * 128;
        gemm_tile128<1>(xb, Wq, bq + n0, nullptr, Qb, E_, E_, QSCALE,
                        m0, n0, n0, As, Bs);
    } else if (x == 16) {
        gemm_tile128<1>(kvb, Wkv, bk, nullptr, KVb, 256, E_, 1.0f,
                        m0, 0, 0, As, Bs);
    } else {
        gemm_tile128<1>(kvb, Wkv, bv, nullptr, KVb, 256, E_, 1.0f,
                        m0, 128, 128, As, Bs);
    }
}

// ---------------- O projection (fp32 out, direct store) ----------------
__global__ __launch_bounds__(256) void gemm_o(
    const bf16_t* __restrict__ A, const bf16_t* __restrict__ W,
    const float* __restrict__ bias, float* __restrict__ Cf)
{
    __shared__ __align__(16) bf16_t As[128 * 64];
    __shared__ __align__(16) bf16_t Bs[128 * 64];
    int n0 = blockIdx.x * 128;
    gemm_tile128<0>(A, W, bias + n0, Cf, nullptr, E_, E_, 1.0f,
                    blockIdx.y * 128, n0, n0, As, Bs);
}

// ---------------- flash-style causal MQA attention ----------------
// Round-6 structure (4 waves x 32 q-rows, dbuf K/V, cross-tile pipeline,
// 1 barrier/tile) with: paired-b32 V staging writes (half the V write issue),
// no exp2 clamp, and row-sums via MFMA-with-ones (racc shares oacc's
// reg<->row layout) -> no epilogue shfl/LDS/barriers.
// Q pre-scaled bf16 [B,S,H,D]; KV interleaved bf16 [B,S,128K|128V]; O bf16.
__global__ __launch_bounds__(256, 2) void mqa_attn(
    const bf16_t* __restrict__ Q, const bf16_t* __restrict__ KV,
    bf16_t* __restrict__ O)
{
    __shared__ __align__(16) bf16_t Kt[2][64][136];   // [buf][k][d], pad 8
    __shared__ __align__(16) bf16_t Vt[2][128][72];   // [buf][d][k], pad 8

    const int bx = blockIdx.x, h = blockIdx.y, b = blockIdx.z;
    const int qb = b ? bx : (15 - bx);                // complementary pairing
    const int tid = threadIdx.x, wave = tid >> 6, lane = tid & 63;
    const int ln = lane & 31, hi = lane >> 5;
    const int q0w = qb * 128 + wave * 32;

    const bf16_t* kvp = KV + (size_t)(b * S_) * 256;

    // Q fragments (B-operand): lane holds Q[q0w+ln][st*16 + hi*8 + j]
    bf16x8 qf[8];
    {
        const bf16_t* qp = Q + ((size_t)(b * S_ + q0w + ln)) * E_ + h * D_ + hi * 8;
#pragma unroll
        for (int st = 0; st < 8; ++st) qf[st] = *(const bf16x8*)(qp + st * 16);
    }

    bf16x8 ones;
#pragma unroll
    for (int j = 0; j < 8; ++j) ones[j] = (bf16_t)1.0f;

    f32x16 oacc[4] = {};
    f32x16 racc = {};
    bf16x8 af[4] = {};

    const int NT = 2 * qb + 2;                 // 64-key tiles for this block
    const int Tw = (q0w + 31) >> 6;            // last active tile for this wave

    bf16x8 kreg[4], vA[2], vB[2];
    auto loadKV = [&](int kt) {
        const int k0 = kt * 64;
#pragma unroll
        for (int i = 0; i < 4; ++i) {
            int c = tid + 256 * i;
            kreg[i] = *(const bf16x8*)(kvp + (size_t)(k0 + (c >> 4)) * 256 + ((c & 15) << 3));
        }
#pragma unroll
        for (int i = 0; i < 2; ++i) {
            int c = tid + 256 * i;
            int n = (c & 31) * 2, d0 = (c >> 5) << 3;
            const bf16_t* src = kvp + (size_t)(k0 + n) * 256 + 128 + d0;
            vA[i] = *(const bf16x8*)src;
            vB[i] = *(const bf16x8*)(src + 256);
        }
    };
    auto stageWrite = [&](int bb) {
#pragma unroll
        for (int i = 0; i < 4; ++i) {
            int c = tid + 256 * i;
            *(bf16x8*)&Kt[bb][c >> 4][(c & 15) << 3] = kreg[i];
        }
#pragma unroll
        for (int i = 0; i < 2; ++i) {
            int c = tid + 256 * i;
            int n = (c & 31) * 2, d0 = (c >> 5) << 3;
#pragma unroll
            for (int j = 0; j < 8; ++j) {
                union { bf16_t h[2]; unsigned u; } w2;
                w2.h[0] = vA[i][j]; w2.h[1] = vB[i][j];
                *(unsigned*)&Vt[bb][d0 + j][n] = w2.u;
            }
        }
    };
    auto doPV = [&](int vb) {
        __builtin_amdgcn_s_setprio(1);
#pragma unroll
        for (int ks = 0; ks < 4; ++ks)
#pragma unroll
            for (int dt = 0; dt < 4; ++dt) {
                bf16x8 vf = *(const bf16x8*)&Vt[vb][dt * 32 + ln][ks * 16 + hi * 8];
                oacc[dt] = __builtin_amdgcn_mfma_f32_32x32x16_bf16(af[ks], vf, oacc[dt], 0, 0, 0);
            }
        __builtin_amdgcn_s_setprio(0);
    };

    // prologue: tile 0 -> buf0; tile 1 -> regs
    loadKV(0);
    stageWrite(0);
    if (NT > 1) loadKV(1);

    for (int t = 0; t < NT; ++t) {
        const int cur = t & 1;
        if (t >= 1 && t - 1 <= Tw) doPV(cur ^ 1);      // PV of previous tile
        __syncthreads();                               // buf[cur^1] free; buf[cur] visible
        if (t + 1 < NT) stageWrite(cur ^ 1);           // hides under QK(t)
        if (t + 2 < NT) loadKV(t + 2);
        if (t <= Tw) {
            // -------- swapped QK^T: sc[ct] = S^T[k][q=ln] --------
            f32x16 sc[2] = {f32x16{}, f32x16{}};
            __builtin_amdgcn_s_setprio(1);
#pragma unroll
            for (int st = 0; st < 8; ++st) {
                bf16x8 qv = qf[st];
#pragma unroll
                for (int ct = 0; ct < 2; ++ct) {
                    bf16x8 kf = *(const bf16x8*)&Kt[cur][ct * 32 + ln][st * 16 + hi * 8];
                    sc[ct] = __builtin_amdgcn_mfma_f32_32x32x16_bf16(kf, qv, sc[ct], 0, 0, 0);
                }
            }
            __builtin_amdgcn_s_setprio(0);
            // -------- mask + exp2 softmax (log2-domain scores) --------
            const int k_base = t * 64;
            const int qi = q0w + ln;
            if (k_base + 63 > q0w) {                   // diag tile: masked path
#pragma unroll
                for (int ct = 0; ct < 2; ++ct)
#pragma unroll
                    for (int r = 0; r < 16; ++r) {
                        int kj = k_base + ct * 32 + (r & 3) + 8 * (r >> 2) + 4 * hi;
                        float s = (kj > qi) ? -1e30f : sc[ct][r];
                        sc[ct][r] = exp2f(s);
                    }
            } else {                                   // interior tile: no mask
#pragma unroll
                for (int ct = 0; ct < 2; ++ct)
#pragma unroll
                    for (int r = 0; r < 16; ++r)
                        sc[ct][r] = exp2f(sc[ct][r]);
            }
            // -------- P -> A-frags in-register (cvt_pk casts + shfl_xor 32) ---
#pragma unroll
            for (int ks = 0; ks < 4; ++ks) {
                const int c = ks >> 1, b8 = (ks & 1) * 8;
                union { bf16_t h[2]; unsigned u; } pk0, pk1, pk2, pk3;
                pk0.h[0] = (bf16_t)sc[c][b8 + 0]; pk0.h[1] = (bf16_t)sc[c][b8 + 1];
                pk1.h[0] = (bf16_t)sc[c][b8 + 2]; pk1.h[1] = (bf16_t)sc[c][b8 + 3];
                pk2.h[0] = (bf16_t)sc[c][b8 + 4]; pk2.h[1] = (bf16_t)sc[c][b8 + 5];
                pk3.h[0] = (bf16_t)sc[c][b8 + 6]; pk3.h[1] = (bf16_t)sc[c][b8 + 7];
                const unsigned U0 = pk0.u, U1 = pk1.u, U2 = pk2.u, U3 = pk3.u;
                const unsigned V0 = __shfl_xor(U0, 32);
                const unsigned V1 = __shfl_xor(U1, 32);
                const unsigned V2 = __shfl_xor(U2, 32);
                const unsigned V3 = __shfl_xor(U3, 32);
                union { unsigned u[4]; bf16x8 v; } W;
                W.u[0] = hi ? V2 : U0;
                W.u[1] = hi ? V3 : U1;
                W.u[2] = hi ? U2 : V0;
                W.u[3] = hi ? U3 : V1;
                af[ks] = W.v;
            }
            // -------- row sums via MFMA-with-ones (racc rows == oacc rows) ----
#pragma unroll
            for (int ks = 0; ks < 4; ++ks)
                racc = __builtin_amdgcn_mfma_f32_32x32x16_bf16(af[ks], ones, racc, 0, 0, 0);
        }
    }
    if (Tw == NT - 1) doPV(1);                 // drain last tile ((NT-1)&1 == 1)

    // -------- epilogue: normalize and store (no LDS, no barriers) --------
    float inv[16];
#pragma unroll
    for (int r = 0; r < 16; ++r) inv[r] = 1.0f / racc[r];
#pragma unroll
    for (int dt = 0; dt < 4; ++dt)
#pragma unroll
        for (int r = 0; r < 16; ++r) {
            int ro = (r & 3) + 8 * (r >> 2) + 4 * hi;
            O[((size_t)(b * S_ + q0w + ro)) * E_ + h * D_ + dt * 32 + ln] =
                (bf16_t)(oacc[dt][r] * inv[r]);
        }
}

// ---------------- launch ----------------
extern "C" void kernel_launch(void* const* d_in, const int* in_sizes, int n_in,
                              void* d_out, int out_size, void* d_ws, size_t ws_size,
                              hipStream_t stream)
{
    const float* x   = (const float*)d_in[0];
    const float* kv  = (const float*)d_in[1];
    const float* Wq  = (const float*)d_in[2];
    const float* bq  = (const float*)d_in[3];
    const float* Wk  = (const float*)d_in[4];
    const float* bk  = (const float*)d_in[5];
    const float* Wv  = (const float*)d_in[6];
    const float* bv  = (const float*)d_in[7];
    const float* Wo  = (const float*)d_in[8];
    const float* bo  = (const float*)d_in[9];
    float* out = (float*)d_out;

    bf16_t* p    = (bf16_t*)d_ws;
    bf16_t* xb   = p;  p += (size_t)BS_ * E_;
    bf16_t* kvb  = p;  p += (size_t)BS_ * E_;
    bf16_t* Wqb  = p;  p += (size_t)E_ * E_;
    bf16_t* Wkvb = p;  p += (size_t)2 * D_ * E_;
    bf16_t* Wob  = p;  p += (size_t)E_ * E_;
    bf16_t* Qb   = p;  p += (size_t)BS_ * E_;
    bf16_t* KVb  = p;  p += (size_t)BS_ * 256;
    bf16_t* Ob   = p;  p += (size_t)BS_ * E_;

    cvt_all<<<dim3(25088), dim3(256), 0, stream>>>(
        x, kv, Wq, Wk, Wv, Wo,
        xb, kvb, Wqb, Wkvb, Wkvb + (size_t)D_ * E_, Wob);

    // fused Q + K + V projections (128x128 tiles, 576 blocks)
    gemm_qkv<<<dim3(18, BS_ / 128), 256, 0, stream>>>(
        xb, kvb, Wqb, Wkvb, bq, bk, bv, Qb, KVb);

    // attention
    mqa_attn<<<dim3(S_ / 128, H_, B_), 256, 0, stream>>>(Qb, KVb, Ob);

    // output projection (128x128 tiles, 512 blocks)
    gemm_o<<<dim3(E_ / 128, BS_ / 128), 256, 0, stream>>>(Ob, Wob, bo, out);
}

// Round 8
// 352.597 us; speedup vs baseline: 1.0137x; 1.0137x over previous
//
#include <hip/hip_runtime.h>

#define B_  2
#define S_  2048
#define E_  2048
#define H_  16
#define D_  128
#define BS_ (B_*S_)

typedef __bf16 bf16_t;
typedef __bf16 bf16x8 __attribute__((ext_vector_type(8)));
typedef __bf16 bf16x4 __attribute__((ext_vector_type(4)));
typedef float  f32x4  __attribute__((ext_vector_type(4)));
typedef float  f32x16 __attribute__((ext_vector_type(16)));

// combined softmax scale: 1/sqrt(128) * log2(e)
#define QSCALE 0.1275174131003543f

// ---------------- async global->LDS, 16B per lane per call ----------------
__device__ __forceinline__ void gld16(const bf16_t* g, bf16_t* l) {
    __builtin_amdgcn_global_load_lds(
        (const __attribute__((address_space(1))) void*)g,
        (__attribute__((address_space(3))) void*)l,
        16, 0, 0);
}

// ---------------- fused fp32 -> bf16 convert (x, kv, 4 weights) ----------------
__global__ void cvt_all(const float* __restrict__ s0, const float* __restrict__ s1,
                        const float* __restrict__ s2, const float* __restrict__ s3,
                        const float* __restrict__ s4, const float* __restrict__ s5,
                        bf16_t* d0, bf16_t* d1, bf16_t* d2,
                        bf16_t* d3, bf16_t* d4, bf16_t* d5)
{
    long i = ((long)blockIdx.x * blockDim.x + threadIdx.x) * 4;
    const float* s; bf16_t* d;
    if      (i <  8388608) { s = s0; d = d0; }
    else if (i < 16777216) { s = s1; d = d1; i -=  8388608; }
    else if (i < 20971520) { s = s2; d = d2; i -= 16777216; }
    else if (i < 21233664) { s = s3; d = d3; i -= 20971520; }
    else if (i < 21495808) { s = s4; d = d4; i -= 21233664; }
    else                   { s = s5; d = d5; i -= 21495808; }
    float4 v = *(const float4*)(s + i);
    bf16x4 o;
    o[0] = (bf16_t)v.x; o[1] = (bf16_t)v.y; o[2] = (bf16_t)v.z; o[3] = (bf16_t)v.w;
    *(bf16x4*)(d + i) = o;
}

// ========== GEMM tile core: 128x128 tile (m97 structure), gld16, K-range ==========
// 4 waves as 2x2; per-wave 64x64 = 4x4 fp32x4 frags; BK=64; LDS 32 KB.
// EP==1: bf16 store of (acc+bias[lcol])*scale. EP==2: bf16 raw store (split-K part).
template<int EP>
__device__ __forceinline__ void gemm_tile128(
    const bf16_t* __restrict__ A, const bf16_t* __restrict__ W,
    const float* __restrict__ bias,
    bf16_t* __restrict__ Cb,
    int N, int K, int kb, int ke, float scale, int m0, int w_n0, int c_n0,
    bf16_t* As, bf16_t* Bs)
{
    const int tid  = threadIdx.x;
    const int wave = tid >> 6, lane = tid & 63;
    const int wm = wave >> 1, wn = wave & 1;
    const int lrow = lane & 15, quad = lane >> 4;
    const int r8 = lane >> 3, c8 = (lane & 7) << 3;

    f32x4 acc[4][4] = {};

    for (int k0 = kb; k0 < ke; k0 += 64) {
        __syncthreads();
#pragma unroll
        for (int j = 0; j < 4; ++j) {
            int base = (wave * 4 + j) * 8;
            gld16(A + (size_t)(m0 + base + r8) * K + k0 + c8, &As[base * 64]);
        }
#pragma unroll
        for (int j = 0; j < 4; ++j) {
            int base = (wave * 4 + j) * 8;
            gld16(W + (size_t)(w_n0 + base + r8) * K + k0 + c8, &Bs[base * 64]);
        }
        __syncthreads();
#pragma unroll
        for (int ks = 0; ks < 2; ++ks) {
            bf16x8 af[4], bfr[4];
#pragma unroll
            for (int mt = 0; mt < 4; ++mt)
                af[mt] = *(const bf16x8*)&As[(wm * 64 + mt * 16 + lrow) * 64 + ks * 32 + quad * 8];
#pragma unroll
            for (int nt = 0; nt < 4; ++nt)
                bfr[nt] = *(const bf16x8*)&Bs[(wn * 64 + nt * 16 + lrow) * 64 + ks * 32 + quad * 8];
#pragma unroll
            for (int mt = 0; mt < 4; ++mt)
#pragma unroll
                for (int nt = 0; nt < 4; ++nt)
                    acc[mt][nt] = __builtin_amdgcn_mfma_f32_16x16x32_bf16(
                        af[mt], bfr[nt], acc[mt][nt], 0, 0, 0);
        }
    }

#pragma unroll
    for (int mt = 0; mt < 4; ++mt) {
#pragma unroll
        for (int nt = 0; nt < 4; ++nt) {
            int lcol = wn * 64 + nt * 16 + lrow;
            int col = c_n0 + lcol;
            float bvv = (EP == 1) ? bias[lcol] : 0.f;
#pragma unroll
            for (int r = 0; r < 4; ++r) {
                int row = m0 + wm * 64 + mt * 16 + quad * 4 + r;
                float v = (EP == 1) ? (acc[mt][nt][r] + bvv) * scale
                                    : acc[mt][nt][r];
                Cb[(size_t)row * N + col] = (bf16_t)v;
            }
        }
    }
}

// ---------------- fused Q (split-K=2) + K + V projection ----------------
// grid (18, 32, 2): x<16 -> Q col-tile x, K-half z -> raw bf16 part Qp[z];
// x==16 (z==0) -> K cols; x==17 (z==0) -> V cols; x>=16,z==1 -> no-op.
__global__ __launch_bounds__(256) void gemm_qkv(
    const bf16_t* __restrict__ xb, const bf16_t* __restrict__ kvb,
    const bf16_t* __restrict__ Wq, const bf16_t* __restrict__ Wkv,
    const float* __restrict__ bk, const float* __restrict__ bv,
    bf16_t* __restrict__ Qp0, bf16_t* __restrict__ Qp1,
    bf16_t* __restrict__ KVb)
{
    __shared__ __align__(16) bf16_t As[128 * 64];
    __shared__ __align__(16) bf16_t Bs[128 * 64];
    const int m0 = blockIdx.y * 128;
    const int x = blockIdx.x, z = blockIdx.z;
    if (x < 16) {
        int n0 = x * 128;
        bf16_t* Qz = z ? Qp1 : Qp0;
        gemm_tile128<2>(xb, Wq, nullptr, Qz, E_, E_,
                        z * 1024, z * 1024 + 1024, 1.0f, m0, n0, n0, As, Bs);
    } else if (z == 0) {
        if (x == 16)
            gemm_tile128<1>(kvb, Wkv, bk, KVb, 256, E_, 0, E_, 1.0f,
                            m0, 0, 0, As, Bs);
        else
            gemm_tile128<1>(kvb, Wkv, bv, KVb, 256, E_, 0, E_, 1.0f,
                            m0, 128, 128, As, Bs);
    }
}

// ---------------- O projection (split-K=2, raw bf16 parts) ----------------
__global__ __launch_bounds__(256) void gemm_o(
    const bf16_t* __restrict__ A, const bf16_t* __restrict__ W,
    bf16_t* __restrict__ Op0, bf16_t* __restrict__ Op1)
{
    __shared__ __align__(16) bf16_t As[128 * 64];
    __shared__ __align__(16) bf16_t Bs[128 * 64];
    const int n0 = blockIdx.x * 128, z = blockIdx.z;
    bf16_t* Oz = z ? Op1 : Op0;
    gemm_tile128<2>(A, W, nullptr, Oz, E_, E_,
                    z * 1024, z * 1024 + 1024, 1.0f,
                    blockIdx.y * 128, n0, n0, As, Bs);
}

// ---------------- merge O partials + bias -> fp32 out ----------------
__global__ __launch_bounds__(256) void merge_out(
    const bf16_t* __restrict__ p0, const bf16_t* __restrict__ p1,
    const float* __restrict__ bo, float* __restrict__ out)
{
    long i = ((long)blockIdx.x * blockDim.x + threadIdx.x) * 4;
    bf16x4 a = *(const bf16x4*)(p0 + i);
    bf16x4 b = *(const bf16x4*)(p1 + i);
    float4 bb = *(const float4*)(bo + (i & 2047));
    float4 o;
    o.x = (float)a[0] + (float)b[0] + bb.x;
    o.y = (float)a[1] + (float)b[1] + bb.y;
    o.z = (float)a[2] + (float)b[2] + bb.z;
    o.w = (float)a[3] + (float)b[3] + bb.w;
    *(float4*)(out + i) = o;
}

// ---------------- flash-style causal MQA attention ----------------
// Round-7 structure (4 waves x 32 q-rows, dbuf K/V, cross-tile pipeline,
// 1 barrier/tile, racc row-sums via MFMA-with-ones). Q fragments are built
// from the two split-K partials: q = (p0 + p1 + bq) * QSCALE.
__global__ __launch_bounds__(256, 2) void mqa_attn(
    const bf16_t* __restrict__ Qp0, const bf16_t* __restrict__ Qp1,
    const float* __restrict__ bq,
    const bf16_t* __restrict__ KV, bf16_t* __restrict__ O)
{
    __shared__ __align__(16) bf16_t Kt[2][64][136];   // [buf][k][d], pad 8
    __shared__ __align__(16) bf16_t Vt[2][128][72];   // [buf][d][k], pad 8

    const int bx = blockIdx.x, h = blockIdx.y, b = blockIdx.z;
    const int qb = b ? bx : (15 - bx);                // complementary pairing
    const int tid = threadIdx.x, wave = tid >> 6, lane = tid & 63;
    const int ln = lane & 31, hi = lane >> 5;
    const int q0w = qb * 128 + wave * 32;

    const bf16_t* kvp = KV + (size_t)(b * S_) * 256;

    // Q fragments (B-operand): lane holds Q[q0w+ln][st*16 + hi*8 + j]
    bf16x8 qf[8];
    {
        size_t off = ((size_t)(b * S_ + q0w + ln)) * E_ + h * D_ + hi * 8;
        const bf16_t* q0p = Qp0 + off;
        const bf16_t* q1p = Qp1 + off;
        const float* bqp = bq + h * D_ + hi * 8;
#pragma unroll
        for (int st = 0; st < 8; ++st) {
            bf16x8 a0 = *(const bf16x8*)(q0p + st * 16);
            bf16x8 a1 = *(const bf16x8*)(q1p + st * 16);
            float4 c0 = *(const float4*)(bqp + st * 16);
            float4 c1 = *(const float4*)(bqp + st * 16 + 4);
            const float* cb0 = (const float*)&c0;
            const float* cb1 = (const float*)&c1;
#pragma unroll
            for (int j = 0; j < 8; ++j) {
                float bb = (j < 4) ? cb0[j] : cb1[j - 4];
                qf[st][j] = (bf16_t)(((float)a0[j] + (float)a1[j] + bb) * QSCALE);
            }
        }
    }

    bf16x8 ones;
#pragma unroll
    for (int j = 0; j < 8; ++j) ones[j] = (bf16_t)1.0f;

    f32x16 oacc[4] = {};
    f32x16 racc = {};
    bf16x8 af[4] = {};

    const int NT = 2 * qb + 2;                 // 64-key tiles for this block
    const int Tw = (q0w + 31) >> 6;            // last active tile for this wave

    bf16x8 kreg[4], vA[2], vB[2];
    auto loadKV = [&](int kt) {
        const int k0 = kt * 64;
#pragma unroll
        for (int i = 0; i < 4; ++i) {
            int c = tid + 256 * i;
            kreg[i] = *(const bf16x8*)(kvp + (size_t)(k0 + (c >> 4)) * 256 + ((c & 15) << 3));
        }
#pragma unroll
        for (int i = 0; i < 2; ++i) {
            int c = tid + 256 * i;
            int n = (c & 31) * 2, d0 = (c >> 5) << 3;
            const bf16_t* src = kvp + (size_t)(k0 + n) * 256 + 128 + d0;
            vA[i] = *(const bf16x8*)src;
            vB[i] = *(const bf16x8*)(src + 256);
        }
    };
    auto stageWrite = [&](int bb) {
#pragma unroll
        for (int i = 0; i < 4; ++i) {
            int c = tid + 256 * i;
            *(bf16x8*)&Kt[bb][c >> 4][(c & 15) << 3] = kreg[i];
        }
#pragma unroll
        for (int i = 0; i < 2; ++i) {
            int c = tid + 256 * i;
            int n = (c & 31) * 2, d0 = (c >> 5) << 3;
#pragma unroll
            for (int j = 0; j < 8; ++j) {
                union { bf16_t h[2]; unsigned u; } w2;
                w2.h[0] = vA[i][j]; w2.h[1] = vB[i][j];
                *(unsigned*)&Vt[bb][d0 + j][n] = w2.u;
            }
        }
    };
    auto doPV = [&](int vb) {
        __builtin_amdgcn_s_setprio(1);
#pragma unroll
        for (int ks = 0; ks < 4; ++ks)
#pragma unroll
            for (int dt = 0; dt < 4; ++dt) {
                bf16x8 vf = *(const bf16x8*)&Vt[vb][dt * 32 + ln][ks * 16 + hi * 8];
                oacc[dt] = __builtin_amdgcn_mfma_f32_32x32x16_bf16(af[ks], vf, oacc[dt], 0, 0, 0);
            }
        __builtin_amdgcn_s_setprio(0);
    };

    // prologue: tile 0 -> buf0; tile 1 -> regs
    loadKV(0);
    stageWrite(0);
    if (NT > 1) loadKV(1);

    for (int t = 0; t < NT; ++t) {
        const int cur = t & 1;
        if (t >= 1 && t - 1 <= Tw) doPV(cur ^ 1);      // PV of previous tile
        __syncthreads();                               // buf[cur^1] free; buf[cur] visible
        if (t + 1 < NT) stageWrite(cur ^ 1);           // hides under QK(t)
        if (t + 2 < NT) loadKV(t + 2);
        if (t <= Tw) {
            // -------- swapped QK^T: sc[ct] = S^T[k][q=ln] --------
            f32x16 sc[2] = {f32x16{}, f32x16{}};
            __builtin_amdgcn_s_setprio(1);
#pragma unroll
            for (int st = 0; st < 8; ++st) {
                bf16x8 qv = qf[st];
#pragma unroll
                for (int ct = 0; ct < 2; ++ct) {
                    bf16x8 kf = *(const bf16x8*)&Kt[cur][ct * 32 + ln][st * 16 + hi * 8];
                    sc[ct] = __builtin_amdgcn_mfma_f32_32x32x16_bf16(kf, qv, sc[ct], 0, 0, 0);
                }
            }
            __builtin_amdgcn_s_setprio(0);
            // -------- mask + exp2 softmax (log2-domain scores) --------
            const int k_base = t * 64;
            const int qi = q0w + ln;
            if (k_base + 63 > q0w) {                   // diag tile: masked path
#pragma unroll
                for (int ct = 0; ct < 2; ++ct)
#pragma unroll
                    for (int r = 0; r < 16; ++r) {
                        int kj = k_base + ct * 32 + (r & 3) + 8 * (r >> 2) + 4 * hi;
                        float s = (kj > qi) ? -1e30f : sc[ct][r];
                        sc[ct][r] = exp2f(s);
                    }
            } else {                                   // interior tile: no mask
#pragma unroll
                for (int ct = 0; ct < 2; ++ct)
#pragma unroll
                    for (int r = 0; r < 16; ++r)
                        sc[ct][r] = exp2f(sc[ct][r]);
            }
            // -------- P -> A-frags in-register (cvt_pk casts + shfl_xor 32) ---
#pragma unroll
            for (int ks = 0; ks < 4; ++ks) {
                const int c = ks >> 1, b8 = (ks & 1) * 8;
                union { bf16_t h[2]; unsigned u; } pk0, pk1, pk2, pk3;
                pk0.h[0] = (bf16_t)sc[c][b8 + 0]; pk0.h[1] = (bf16_t)sc[c][b8 + 1];
                pk1.h[0] = (bf16_t)sc[c][b8 + 2]; pk1.h[1] = (bf16_t)sc[c][b8 + 3];
                pk2.h[0] = (bf16_t)sc[c][b8 + 4]; pk2.h[1] = (bf16_t)sc[c][b8 + 5];
                pk3.h[0] = (bf16_t)sc[c][b8 + 6]; pk3.h[1] = (bf16_t)sc[c][b8 + 7];
                const unsigned U0 = pk0.u, U1 = pk1.u, U2 = pk2.u, U3 = pk3.u;
                const unsigned V0 = __shfl_xor(U0, 32);
                const unsigned V1 = __shfl_xor(U1, 32);
                const unsigned V2 = __shfl_xor(U2, 32);
                const unsigned V3 = __shfl_xor(U3, 32);
                union { unsigned u[4]; bf16x8 v; } W;
                W.u[0] = hi ? V2 : U0;
                W.u[1] = hi ? V3 : U1;
                W.u[2] = hi ? U2 : V0;
                W.u[3] = hi ? U3 : V1;
                af[ks] = W.v;
            }
            // -------- row sums via MFMA-with-ones (racc rows == oacc rows) ----
#pragma unroll
            for (int ks = 0; ks < 4; ++ks)
                racc = __builtin_amdgcn_mfma_f32_32x32x16_bf16(af[ks], ones, racc, 0, 0, 0);
        }
    }
    if (Tw == NT - 1) doPV(1);                 // drain last tile ((NT-1)&1 == 1)

    // -------- epilogue: normalize and store (no LDS, no barriers) --------
    float inv[16];
#pragma unroll
    for (int r = 0; r < 16; ++r) inv[r] = 1.0f / racc[r];
#pragma unroll
    for (int dt = 0; dt < 4; ++dt)
#pragma unroll
        for (int r = 0; r < 16; ++r) {
            int ro = (r & 3) + 8 * (r >> 2) + 4 * hi;
            O[((size_t)(b * S_ + q0w + ro)) * E_ + h * D_ + dt * 32 + ln] =
                (bf16_t)(oacc[dt][r] * inv[r]);
        }
}

// ---------------- launch ----------------
extern "C" void kernel_launch(void* const* d_in, const int* in_sizes, int n_in,
                              void* d_out, int out_size, void* d_ws, size_t ws_size,
                              hipStream_t stream)
{
    const float* x   = (const float*)d_in[0];
    const float* kv  = (const float*)d_in[1];
    const float* Wq  = (const float*)d_in[2];
    const float* bq  = (const float*)d_in[3];
    const float* Wk  = (const float*)d_in[4];
    const float* bk  = (const float*)d_in[5];
    const float* Wv  = (const float*)d_in[6];
    const float* bv  = (const float*)d_in[7];
    const float* Wo  = (const float*)d_in[8];
    const float* bo  = (const float*)d_in[9];
    float* out = (float*)d_out;

    bf16_t* p    = (bf16_t*)d_ws;
    bf16_t* xb   = p;  p += (size_t)BS_ * E_;   // reused as O-part 0 after qkv
    bf16_t* kvb  = p;  p += (size_t)BS_ * E_;   // reused as O-part 1 after qkv
    bf16_t* Wqb  = p;  p += (size_t)E_ * E_;
    bf16_t* Wkvb = p;  p += (size_t)2 * D_ * E_;
    bf16_t* Wob  = p;  p += (size_t)E_ * E_;
    bf16_t* Qp0  = p;  p += (size_t)BS_ * E_;
    bf16_t* KVb  = p;  p += (size_t)BS_ * 256;
    bf16_t* Ob   = p;  p += (size_t)BS_ * E_;
    bf16_t* Qp1  = p;  p += (size_t)BS_ * E_;

    cvt_all<<<dim3(25088), dim3(256), 0, stream>>>(
        x, kv, Wq, Wk, Wv, Wo,
        xb, kvb, Wqb, Wkvb, Wkvb + (size_t)D_ * E_, Wob);

    // Q (split-K=2, 1024 blocks) + K + V projections
    gemm_qkv<<<dim3(18, BS_ / 128, 2), 256, 0, stream>>>(
        xb, kvb, Wqb, Wkvb, bk, bv, Qp0, Qp1, KVb);

    // attention (absorbs Q partial merge + bias + scale)
    mqa_attn<<<dim3(S_ / 128, H_, B_), 256, 0, stream>>>(Qp0, Qp1, bq, KVb, Ob);

    // output projection (split-K=2, 1024 blocks) -> partials in xb/kvb
    gemm_o<<<dim3(E_ / 128, BS_ / 128, 2), 256, 0, stream>>>(Ob, Wob, xb, kvb);

    // merge partials + bias -> fp32 out
    merge_out<<<dim3(8192), dim3(256), 0, stream>>>(xb, kvb, bo, out);
}